// Round 15
// baseline (3068.971 us; speedup 1.0000x reference)
//
#include <hip/hip_runtime.h>
#include <math.h>

// Glacier SIA stepper. 256 persistent blocks x 256 threads: band w=blk>>1
// (4 owned rows), half=blk&1 (256 columns) -> ALL 256 CUs, 4 waves/CU,
// per-wave instruction stream unchanged vs R14 (per-CU issue time halves).
// Row-halo protocol identical to R14 (epoch-tagged words, depth-2 parity,
// register consumption + shfl/seam). NEW: column seam between halves via
// two special edge threads:
//   specL = (half0, j=255, jg=255): needs ghost col 256.
//     - dHdt: ze from rzs[] (carried, state-k) ;
//     - phase2: h01/z01 from rhn/rzs spun AFTER sync2 (tag k+1, posted by
//       specR's part B same step) -> carried to next step's dHdt.
//     - posts gHL (6 hn rows, part B) + gDL (5 D rows, phase 2).
//   specR = (half1, j=0, jg=256): needs ghost col 255.
//     - spins gHL/gDL at step top (tag k, prev step) -> gzs/gd registers;
//       computes all 6 dHdt rows in a dedicated branch.
//     - posts gHR (6 hn rows, part B).
// Acyclic: specL.phase2(k) <- specR.partB(k) <- dt(k) <- ring(k-1).
// Ring: 256 slots, all 4 waves gather, tagged gm[4] LDS words.
//
// ws layout (bytes):
//   0        : ull ring[2][256] lines (128 B)      (64 KB)
//   65536    : ull rowhalo[4][2][128][512]         (4 MB: upH,upD,dnH,dnD)
//   4259840  : ull ghost: gHL[2][128][8], gDL[...], gHR[...]  (48 KB)

#define NN 512
#define MM (NN * NN)
#define NSTEPS 400
#define NBANDS 128
#define NBLK 256
#define HR 4
#define TPB 256

typedef unsigned long long ull;

__device__ __forceinline__ ull ald(const ull* p) {
  return __hip_atomic_load(p, __ATOMIC_RELAXED, __HIP_MEMORY_SCOPE_AGENT);
}
__device__ __forceinline__ void asto(ull* p, ull v) {
  __hip_atomic_store(p, v, __ATOMIC_RELAXED, __HIP_MEMORY_SCOPE_AGENT);
}
__device__ __forceinline__ ull lld(const ull* p) {
  return __hip_atomic_load(p, __ATOMIC_RELAXED, __HIP_MEMORY_SCOPE_WORKGROUP);
}
__device__ __forceinline__ void lst(ull* p, ull v) {
  __hip_atomic_store(p, v, __ATOMIC_RELAXED, __HIP_MEMORY_SCOPE_WORKGROUP);
}
__device__ __forceinline__ float spinf(const ull* p, unsigned kk) {
  ull v = ald(p);
  while ((unsigned)(v >> 32) < kk) { __builtin_amdgcn_s_sleep(1); v = ald(p); }
  return __uint_as_float((unsigned)v);
}

__global__ __launch_bounds__(TPB)
void glacier_kernel(const float* __restrict__ Zt,
                    const float* __restrict__ precip,
                    const float* __restrict__ Tm,
                    const float* __restrict__ Ts,
                    float* __restrict__ out,        // [3*MM]: H1, H2, H
                    ull* __restrict__ ring,         // [2][256] lines
                    ull* __restrict__ halo,         // row halos
                    ull* __restrict__ ghost) {      // column ghosts
  __shared__ float Zs2[2][HR + 4][256];
  __shared__ float DB[HR + 3][256];
  __shared__ float HnB[HR + 2][256];
  __shared__ ull gm[4];
  __shared__ unsigned lmx[2], lcnt[2];

  ull* upH = halo;                        // [2][NBANDS][NN] each
  ull* upD = halo + 2 * NBANDS * NN;
  ull* dnH = halo + 4 * NBANDS * NN;
  ull* dnD = halo + 6 * NBANDS * NN;
  ull* gHL = ghost;                       // [2][NBANDS][8] each
  ull* gDL = ghost + 2 * NBANDS * 8;
  ull* gHR = ghost + 4 * NBANDS * 8;

  const int w = blockIdx.x >> 1;          // band
  const int half = blockIdx.x & 1;
  const int j = threadIdx.x;              // local column 0..255
  const int jg = (half << 8) | j;         // global column
  const int lane = j & 63;
  const int jm = (j > 0) ? j - 1 : 0;     // clamped local indices
  const int jp = (j < 255) ? j + 1 : 255;
  const int a = w * HR;                   // first owned row
  const bool hasT = (w > 0), hasB = (w < NBANDS - 1);
  const bool specR = (half == 1) && (j == 0);     // jg=256, ghost col 255
  const bool specL = (half == 0) && (j == 255);   // jg=255, ghost col 256
  const float TmTs = Tm[0] + Ts[0];
  const double RG = 910.0 * 9.81;
  const float CDIF = (float)(1e-16 * RG * RG * RG);
  const float C_Q = 1.25e-5f;
  const float C_S2 = 6.25e-6f;
  const size_t wofs = (size_t)w * NN;

  float ztreg[HR + 4];
  float hcur[HR + 2];
  float smbreg[HR + 2];

  // ---- prologue
#pragma unroll
  for (int ls = 0; ls < HR + 4; ++ls) {
    int r = a - 2 + ls;
    float zt = (r >= 0 && r < NN) ? Zt[r * NN + jg] : 0.f;
    ztreg[ls] = zt;
    Zs2[0][ls][j] = zt;                   // H = 0
  }
#pragma unroll
  for (int ln = 0; ln < HR + 2; ++ln) {
    int r = a - 1 + ln;
    hcur[ln] = 0.f;
    float sm = 0.f;
    if (r >= 0 && r < NN) {
      float T = TmTs - 0.006f * ztreg[ln + 1];
      sm = precip[r * NN + jg] - 0.5f * fmaxf(T, 0.f);
    }
    smbreg[ln] = sm;
  }
#pragma unroll
  for (int ld = 0; ld < HR + 3; ++ld) DB[ld][j] = 1e-10f;
#pragma unroll
  for (int rr = 0; rr < HR; ++rr) {
    int id = (a + rr) * NN + jg;
    out[id] = 0.f;
    out[MM + id] = 0.f;
  }
  if (j == 0) { lmx[0] = 0u; lmx[1] = 0u; lcnt[0] = 0u; lcnt[1] = 0u;
                gm[0] = 0ull; gm[1] = 0ull; gm[2] = 0ull; gm[3] = 0ull; }
  // row-halo registers (own column)
  float zs0r = ztreg[0], zs7r = ztreg[HR + 3];
  float d0r = 1e-10f, d6r = 1e-10f;
  const ull initD = (ull)__float_as_uint(1e-10f);
  // column-ghost registers
  float gzt[6], gzs[6], gd[5];            // specR: col 255, rows a-1..a+4 / D a-1..a+3
  float rzt[6], rzs[6];                   // specL: col 256
#pragma unroll
  for (int r = 0; r < 6; ++r) {
    int row = a - 1 + r;
    float ztL = (specR && row >= 0 && row < NN) ? Zt[row * NN + 255] : 0.f;
    float ztR = (specL && row >= 0 && row < NN) ? Zt[row * NN + 256] : 0.f;
    gzt[r] = ztL; gzs[r] = ztL;
    rzt[r] = ztR; rzs[r] = ztR;
    if (r < 5) gd[r] = 1e-10f;
  }
  __syncthreads();

  float time = 0.f, t_last = 0.f;
  int idx = 0;
  bool s1 = false, s2 = false;

  for (int k = 0; k < NSTEPS; ++k) {
    if (time >= 200.0f) break;            // uniform (dt identical)

    const int p = k & 1;
    const size_t pc = (size_t)(k & 1) * NBANDS * NN;
    const size_t pn = (size_t)((k + 1) & 1) * NBANDS * NN;
    const size_t gpc = (size_t)(k & 1) * NBANDS * 8;
    const size_t gpn = (size_t)((k + 1) & 1) * NBANDS * 8;
    const ull tg = ((ull)(unsigned)(k + 1)) << 32;
    ull* ringp = ring + (size_t)(k & 1) * NBLK * 16;

    if (j == 0) { lmx[(k + 1) & 1] = 0u; lcnt[(k + 1) & 1] = 0u; }

    // ---- top samples
    bool pre = (time - t_last) >= 4.0f;
    int idxn = min(idx + 1, 63);
    float pf[HR + 2];
    if (pre) {
      const float* prowN = precip + (size_t)idxn * MM;
#pragma unroll
      for (int ln = 0; ln < HR + 2; ++ln) {
        int i = a - 1 + ln;
        pf[ln] = (i >= 0 && i < NN) ? prowN[i * NN + jg] : 0.f;
      }
    } else {
#pragma unroll
      for (int ln = 0; ln < HR + 2; ++ln) pf[ln] = 0.f;
    }
    const ull *pHt = nullptr, *pDt = nullptr, *pHb = nullptr, *pDb = nullptr;
    const ull *pDtm = nullptr, *pDbm = nullptr;
    ull vHt = 0, vDt = 0, vHb = 0, vDb = 0;
    ull vDtm = initD, vDbm = initD;
    const ull* gp = ringp + j * 16;       // ring slot j (256 slots, 256 thr)
    ull gv = 0;
    if (k > 0) {
      if (hasT) {
        pHt = dnH + pc + (size_t)(w - 1) * NN + jg;
        pDt = dnD + pc + (size_t)(w - 1) * NN + jg;
        vHt = ald(pHt);
        if (jg < NN - 1) vDt = ald(pDt);
        if (lane == 0 && jg > 0) { pDtm = dnD + pc + (size_t)(w - 1) * NN + (jg - 1); vDtm = ald(pDtm); }
      }
      if (hasB) {
        pHb = upH + pc + (size_t)(w + 1) * NN + jg;
        pDb = upD + pc + (size_t)(w + 1) * NN + jg;
        vHb = ald(pHb);
        if (jg < NN - 1) vDb = ald(pDb);
        if (lane == 0 && jg > 0) { pDbm = upD + pc + (size_t)(w + 1) * NN + (jg - 1); vDbm = ald(pDbm); }
      }
      gv = ald(gp);
    }
    asm volatile("" ::: "memory");

    // ---- part A mid: rows a..a+3 (normal threads; specR excluded)
    float dHdt[HR + 2];
#pragma unroll
    for (int ln = 1; ln <= HR; ++ln) {
      int i = a - 1 + ln;
      float v = 0.f;
      if (i > 0 && i < NN - 1 && jg > 0 && jg < NN - 1 && !specR) {
        int li = ln + 1;
        float zc = Zs2[p][li][j];
        float zw = Zs2[p][li][jm];
        float ze = specL ? rzs[ln] : Zs2[p][li][jp];
        float zn = Zs2[p][li - 1][j];
        float zs_ = Zs2[p][li + 1][j];
        float d00 = DB[ln][jm], d01 = DB[ln][j];
        float d10 = DB[ln + 1][jm], d11 = DB[ln + 1][j];
        v = C_Q * (((d01 + d11) * (ze - zc) - (d00 + d10) * (zc - zw)) +
                   ((d10 + d11) * (zs_ - zc) - (d00 + d01) * (zc - zn)));
      }
      dHdt[ln] = v;
    }

    // ---- spins: row halos -> registers; specR column ghosts; ring gather
    if (k > 0) {
      if (pHt) {
        while ((unsigned)(vHt >> 32) < (unsigned)k) { __builtin_amdgcn_s_sleep(1); vHt = ald(pHt); }
        if (jg < NN - 1)
          while ((unsigned)(vDt >> 32) < (unsigned)k) { __builtin_amdgcn_s_sleep(1); vDt = ald(pDt); }
        if (pDtm)
          while ((unsigned)(vDtm >> 32) < (unsigned)k) { __builtin_amdgcn_s_sleep(1); vDtm = ald(pDtm); }
        zs0r = ztreg[0] + __uint_as_float((unsigned)vHt);
        if (jg < NN - 1) d0r = __uint_as_float((unsigned)vDt);
      }
      if (pHb) {
        while ((unsigned)(vHb >> 32) < (unsigned)k) { __builtin_amdgcn_s_sleep(1); vHb = ald(pHb); }
        if (jg < NN - 1)
          while ((unsigned)(vDb >> 32) < (unsigned)k) { __builtin_amdgcn_s_sleep(1); vDb = ald(pDb); }
        if (pDbm)
          while ((unsigned)(vDbm >> 32) < (unsigned)k) { __builtin_amdgcn_s_sleep(1); vDbm = ald(pDbm); }
        zs7r = ztreg[HR + 3] + __uint_as_float((unsigned)vHb);
        if (jg < NN - 1) d6r = __uint_as_float((unsigned)vDb);
      }
      if (specR) {                        // ghost col 255, prev-step posts
        const ull* hb = gHL + gpc + (size_t)w * 8;
        const ull* db = gDL + gpc + (size_t)w * 8;
#pragma unroll
        for (int r = 0; r < 6; ++r) {
          int row = a - 1 + r;
          if (row >= 0 && row < NN) gzs[r] = gzt[r] + spinf(hb + r, (unsigned)k);
        }
#pragma unroll
        for (int r = 0; r < 5; ++r) {
          int row = a - 1 + r;
          if (row >= 0 && row < NN - 1) gd[r] = spinf(db + r, (unsigned)k);
        }
      }
      // ring gather: every thread one slot; 4 tagged partials
      while ((unsigned)(gv >> 32) < (unsigned)k) { __builtin_amdgcn_s_sleep(1); gv = ald(gp); }
      float lm = __uint_as_float((unsigned)gv);
      for (int off = 32; off; off >>= 1) lm = fmaxf(lm, __shfl_xor(lm, off));
      if (lane == 0)
        lst(&gm[j >> 6], ((ull)(unsigned)k << 32) | (ull)__float_as_uint(lm));
    }

    // ---- part A edges: rows a-1, a+4 (normal + specL); then specR all rows
    {
      float dW0 = __shfl_up(d0r, 1);
      float dW6 = __shfl_up(d6r, 1);
      if (lane == 0) {
        dW0 = __uint_as_float((unsigned)vDtm);
        dW6 = __uint_as_float((unsigned)vDbm);
      }
      int i0 = a - 1;
      float v0 = 0.f;
      if (i0 > 0 && i0 < NN - 1 && jg > 0 && jg < NN - 1 && !specR) {
        float zc = Zs2[p][1][j], zw = Zs2[p][1][jm];
        float ze = specL ? rzs[0] : Zs2[p][1][jp];
        float zn = zs0r, zs_ = Zs2[p][2][j];
        float d00 = dW0, d01 = d0r;
        float d10 = DB[1][jm], d11 = DB[1][j];
        v0 = C_Q * (((d01 + d11) * (ze - zc) - (d00 + d10) * (zc - zw)) +
                    ((d10 + d11) * (zs_ - zc) - (d00 + d01) * (zc - zn)));
      }
      dHdt[0] = v0;
      int i5 = a + HR;
      float v5 = 0.f;
      if (i5 > 0 && i5 < NN - 1 && jg > 0 && jg < NN - 1 && !specR) {
        float zc = Zs2[p][HR + 2][j], zw = Zs2[p][HR + 2][jm];
        float ze = specL ? rzs[5] : Zs2[p][HR + 2][jp];
        float zn = Zs2[p][HR + 1][j], zs_ = zs7r;
        float d00 = DB[HR + 1][jm], d01 = DB[HR + 1][j];
        float d10 = dW6, d11 = d6r;
        v5 = C_Q * (((d01 + d11) * (ze - zc) - (d00 + d10) * (zc - zw)) +
                    ((d10 + d11) * (zs_ - zc) - (d00 + d01) * (zc - zn)));
      }
      dHdt[HR + 1] = v5;
      if (specR) {                        // all 6 rows, ghost west sources
#pragma unroll
        for (int ln = 0; ln < HR + 2; ++ln) {
          int i = a - 1 + ln;
          float v = 0.f;
          if (i > 0 && i < NN - 1) {
            int li = ln + 1;
            float zc = Zs2[p][li][0];
            float ze = Zs2[p][li][1];
            float zn = (ln == 0) ? zs0r : Zs2[p][li - 1][0];
            float zs_ = (ln == HR + 1) ? zs7r : Zs2[p][li + 1][0];
            float zw = gzs[ln];
            float d01 = (ln == 0) ? d0r : DB[ln][0];
            float d11 = (ln == HR + 1) ? d6r : DB[ln + 1][0];
            float d00 = (ln == 0) ? dW0 : gd[ln - 1];
            float d10 = (ln == HR + 1) ? dW6 : gd[ln];
            v = C_Q * (((d01 + d11) * (ze - zc) - (d00 + d10) * (zc - zw)) +
                       ((d10 + d11) * (zs_ - zc) - (d00 + d01) * (zc - zn)));
          }
          dHdt[ln] = v;
        }
      }
    }

    // ---- dt-independent sum
    float sd[HR + 2];
#pragma unroll
    for (int ln = 0; ln < HR + 2; ++ln) sd[ln] = dHdt[ln] + smbreg[ln];

    // ---- dt via tagged LDS gather words
    float maxD;
    if (k == 0) {
      maxD = 1e-10f;
    } else {
      maxD = 0.f;
#pragma unroll
      for (int q = 0; q < 4; ++q) {
        ull g = lld(&gm[q]);
        while ((unsigned)(g >> 32) < (unsigned)k) { __builtin_amdgcn_s_sleep(1); g = lld(&gm[q]); }
        maxD = fmaxf(maxD, __uint_as_float((unsigned)g));
      }
    }
    float dt = fminf(40000.0f / (2.7f * maxD), 1.0f);
    float tnew = time + dt;
    bool cap1 = (!s1) && (tnew >= 120.0f);
    bool cap2 = (!s2) && (tnew >= 160.0f);
    bool do_upd = (tnew - t_last) >= 5.0f;

    // ---- part B: H update, row-halo posts, column-ghost H posts
    float hnxt[HR + 2];
#pragma unroll
    for (int ln = 0; ln < HR + 2; ++ln) {
      int i = a - 1 + ln;
      float hnew = 0.f;
      if (i >= 0 && i < NN) {
        if (i > 0 && i < NN - 1 && jg > 0 && jg < NN - 1)
          hnew = fmaxf(fmaf(dt, sd[ln], hcur[ln]), 0.f);
        float zsn = ztreg[ln + 1] + hnew;
        HnB[ln][j] = hnew;
        Zs2[p ^ 1][ln + 1][j] = zsn;
        if (ln == 2) asto(upH + pn + wofs + jg, tg | (ull)__float_as_uint(hnew));
        if (ln == 3) asto(dnH + pn + wofs + jg, tg | (ull)__float_as_uint(hnew));
        if (specL) asto(gHL + gpn + (size_t)w * 8 + ln, tg | (ull)__float_as_uint(hnew));
        if (specR) asto(gHR + gpn + (size_t)w * 8 + ln, tg | (ull)__float_as_uint(hnew));
        if (i >= a && i < a + HR) {
          int id = i * NN + jg;
          if (cap1) out[id] = hnew;
          if (cap2) out[MM + id] = hnew;
        }
        if (do_upd)
          smbreg[ln] = pf[ln] - 0.5f * fmaxf(TmTs - 0.006f * zsn, 0.f);
      }
      hnxt[ln] = hnew;
    }
    __syncthreads();                      // sync2: HnB/Zs2^1 visible

    // ---- specL: same-step ghost hn spin (posted by specR's part B)
    float rhn[6] = {0.f, 0.f, 0.f, 0.f, 0.f, 0.f};
    if (specL) {
      const ull* hb = gHR + gpn + (size_t)w * 8;
#pragma unroll
      for (int r = 0; r < 6; ++r) {
        int row = a - 1 + r;
        if (row >= 0 && row < NN) {
          rhn[r] = spinf(hb + r, (unsigned)(k + 1));
          rzs[r] = rzt[r] + rhn[r];       // state k+1, carried to next dHdt
        }
      }
    }

    // ---- phase 2: D rows a-1..a+3, posts, block max
    float lmax = 0.f;
#pragma unroll
    for (int ln = 0; ln < HR + 1; ++ln) {
      int r = a - 1 + ln;
      if (r >= 0 && r < NN - 1 && jg < NN - 1) {
        float h00 = HnB[ln][j];
        float h01 = specL ? rhn[ln] : HnB[ln][jp];
        float h10 = HnB[ln + 1][j];
        float h11 = specL ? rhn[ln + 1] : HnB[ln + 1][jp];
        float z00 = Zs2[p ^ 1][ln + 1][j];
        float z01 = specL ? rzs[ln] : Zs2[p ^ 1][ln + 1][jp];
        float z10 = Zs2[p ^ 1][ln + 2][j];
        float z11 = specL ? rzs[ln + 1] : Zs2[p ^ 1][ln + 2][jp];
        float havg = 0.25f * (((h00 + h11) + h01) + h10);
        float u = (z01 - z00) + (z11 - z10);
        float vv = (z10 - z00) + (z11 - z01);
        float s2 = C_S2 * (u * u + vv * vv) + 1e-10f;
        float h2 = havg * havg;
        float h4 = h2 * h2;
        float h5 = h4 * havg;
        float d = CDIF * h5 * s2 + 1e-10f;
        DB[ln + 1][j] = d;
        if (ln == 1) asto(upD + pn + wofs + jg, tg | (ull)__float_as_uint(d));
        if (ln == 3) asto(dnD + pn + wofs + jg, tg | (ull)__float_as_uint(d));
        if (specL) asto(gDL + gpn + (size_t)w * 8 + ln, tg | (ull)__float_as_uint(d));
        lmax = fmaxf(lmax, d);
      }
    }
    for (int off = 32; off; off >>= 1) lmax = fmaxf(lmax, __shfl_xor(lmax, off));
    if (lane == 0) {
      atomicMax(&lmx[k & 1], __float_as_uint(lmax));
      unsigned c = atomicAdd(&lcnt[k & 1], 1u);
      if (c == 3u) {                      // 4 waves
        unsigned mv = atomicAdd(&lmx[k & 1], 0u);
        asto(ring + (size_t)((k + 1) & 1) * NBLK * 16 + (size_t)blockIdx.x * 16,
             ((ull)(unsigned)(k + 1) << 32) | (ull)mv);
      }
    }

    // ---- bookkeeping + step-close barrier
#pragma unroll
    for (int ln = 0; ln < HR + 2; ++ln) hcur[ln] = hnxt[ln];
    time = tnew;
    s1 = s1 || cap1;
    s2 = s2 || cap2;
    if (do_upd) { idx = idxn; t_last = tnew; }
    __syncthreads();                      // sync3
  }

  // ---- final H
#pragma unroll
  for (int rr = 0; rr < HR; ++rr)
    out[2 * MM + (a + rr) * NN + jg] = hcur[rr + 1];
}

extern "C" void kernel_launch(void* const* d_in, const int* in_sizes, int n_in,
                              void* d_out, int out_size, void* d_ws, size_t ws_size,
                              hipStream_t stream) {
  const float* Zt = (const float*)d_in[0];
  const float* precip = (const float*)d_in[1];
  const float* Tm = (const float*)d_in[2];
  const float* Ts = (const float*)d_in[3];
  float* out = (float*)d_out;

  ull* ring = (ull*)d_ws;                              // 64 KB
  ull* halo = (ull*)((char*)d_ws + 65536);             // 4 MB row halos
  ull* ghost = (ull*)((char*)d_ws + 65536 + 4194304);  // 48 KB column ghosts

  // zero ring + halo tags + ghost tags
  hipMemsetAsync(d_ws, 0, 65536 + 4194304 + 49152, stream);
  glacier_kernel<<<NBLK, TPB, 0, stream>>>(Zt, precip, Tm, Ts, out,
                                           ring, halo, ghost);
}

// Round 16
// 1267.875 us; speedup vs baseline: 2.4206x; 2.4206x over previous
//
#include <hip/hip_runtime.h>
#include <math.h>

// Glacier SIA stepper. 128 persistent blocks x 512 threads (R10 geometry).
// R12 (BEST KNOWN, 1270 us): global-gather decoupled from barriers. sync1
// orders only neighbor halo staging; waves 0,1 gather the 128 ring slots
// AFTER sync1 (overlapping the other 6 waves' edge-row compute) and publish
// {epoch<<32|max} as a tagged LDS word; consumers spin on it (LDS RT, no
// barrier) right before the dt-dependent H-update. sd = dHdt+smb precomputed
// so part B is 1 fma. Epoch-tagged halo words + depth-2 parity + pre-barrier
// ring post. Strength-reduced arithmetic (folded /200, sqrt^2 identity).
//
// Structural floor (measured across R10/R12/R13/R14/R8/R11/R15): ~3.2 us/step
// = MALL post->observe RT + H/D update chain + barrier/skew, x400 sequential
// steps with an irreducible grid-wide max(D) dependency per step.
//
// ws layout (bytes):
//   0      : ull ring[2][128] lines (stride 128 B) {epoch<<32 | blockMax}
//   32768  : ull halo[4][2][NW][NN]  (upH, upD, dnH, dnD; 4 MB)

#define NN 512
#define MM (NN * NN)
#define NSTEPS 400
#define NW 128
#define HR 4
#define TPB 512

typedef unsigned long long ull;

__device__ __forceinline__ ull ald(const ull* p) {
  return __hip_atomic_load(p, __ATOMIC_RELAXED, __HIP_MEMORY_SCOPE_AGENT);
}
__device__ __forceinline__ void asto(ull* p, ull v) {
  __hip_atomic_store(p, v, __ATOMIC_RELAXED, __HIP_MEMORY_SCOPE_AGENT);
}
__device__ __forceinline__ ull lld(const ull* p) {
  return __hip_atomic_load(p, __ATOMIC_RELAXED, __HIP_MEMORY_SCOPE_WORKGROUP);
}
__device__ __forceinline__ void lst(ull* p, ull v) {
  __hip_atomic_store(p, v, __ATOMIC_RELAXED, __HIP_MEMORY_SCOPE_WORKGROUP);
}

__global__ __launch_bounds__(TPB)
void glacier_kernel(const float* __restrict__ Zt,
                    const float* __restrict__ precip,
                    const float* __restrict__ Tm,
                    const float* __restrict__ Ts,
                    float* __restrict__ out,        // [3*MM]: H1, H2, H
                    ull* __restrict__ ring,         // [2][128] lines
                    ull* __restrict__ halo) {       // [4][2][NW][NN]
  __shared__ float Zs2[2][HR + 4][NN];
  __shared__ float DB[HR + 3][NN];
  __shared__ float HnB[HR + 2][NN];
  __shared__ ull gm[2];               // tagged {epoch<<32 | partial-max bits}
  __shared__ unsigned lmx[2], lcnt[2];

  ull* upH = halo;                    // [2][NW][NN] each
  ull* upD = halo + 2 * NW * NN;
  ull* dnH = halo + 4 * NW * NN;
  ull* dnD = halo + 6 * NW * NN;

  const int w = blockIdx.x;
  const int j = threadIdx.x;          // column
  const int lane = j & 63;
  const int a = w * HR;               // first owned row
  const bool hasT = (w > 0), hasB = (w < NW - 1);
  const float TmTs = Tm[0] + Ts[0];
  const double RG = 910.0 * 9.81;
  const float CDIF = (float)(1e-16 * RG * RG * RG);
  const float C_Q = 1.25e-5f;         // folded flux scaling
  const float C_S2 = 6.25e-6f;        // (0.5/200)^2 slope scaling
  const size_t wofs = (size_t)w * NN;

  float ztreg[HR + 4];
  float hcur[HR + 2];
  float smbreg[HR + 2];

  // ---- prologue (no cross-block deps)
#pragma unroll
  for (int ls = 0; ls < HR + 4; ++ls) {
    int r = a - 2 + ls;
    float zt = (r >= 0 && r < NN) ? Zt[r * NN + j] : 0.f;
    ztreg[ls] = zt;
    Zs2[0][ls][j] = zt;               // H = 0
  }
#pragma unroll
  for (int ln = 0; ln < HR + 2; ++ln) {
    int r = a - 1 + ln;
    hcur[ln] = 0.f;
    float sm = 0.f;
    if (r >= 0 && r < NN) {
      float T = TmTs - 0.006f * ztreg[ln + 1];
      sm = precip[r * NN + j] - 0.5f * fmaxf(T, 0.f);
    }
    smbreg[ln] = sm;
  }
#pragma unroll
  for (int ld = 0; ld < HR + 3; ++ld) DB[ld][j] = 1e-10f;    // D(H=0) exactly
#pragma unroll
  for (int rr = 0; rr < HR; ++rr) {
    int id = (a + rr) * NN + j;
    out[id] = 0.f;
    out[MM + id] = 0.f;
  }
  if (j == 0) { lmx[0] = 0u; lmx[1] = 0u; lcnt[0] = 0u; lcnt[1] = 0u;
                gm[0] = 0ull; gm[1] = 0ull; }
  __syncthreads();                    // prologue LDS visible

  float time = 0.f, t_last = 0.f;
  int idx = 0;
  bool s1 = false, s2 = false;

  for (int k = 0; k < NSTEPS; ++k) {
    if (time >= 200.0f) break;                  // uniform (dt identical)

    const int p = k & 1;
    const size_t pc = (size_t)(k & 1) * NW * NN;        // consume parity
    const size_t pn = (size_t)((k + 1) & 1) * NW * NN;  // produce parity
    const ull tg = ((ull)(unsigned)(k + 1)) << 32;      // produce tag
    ull* ringp = ring + (size_t)(k & 1) * NW * 16;

    // reset the LDS max/cnt slot step k+1 will use (safe: sync3(k-1) passed)
    if (j == 0) { lmx[(k + 1) & 1] = 0u; lcnt[(k + 1) & 1] = 0u; }

    // ---- top samples (issue early; checked after mid compute)
    bool pre = (time - t_last) >= 4.0f;         // exact-safe precip gate
    int idxn = min(idx + 1, 63);
    float pf[HR + 2];
    if (pre) {
      const float* prowN = precip + (size_t)idxn * MM;
#pragma unroll
      for (int ln = 0; ln < HR + 2; ++ln) {
        int i = a - 1 + ln;
        pf[ln] = (i >= 0 && i < NN) ? prowN[i * NN + j] : 0.f;
      }
    } else {
#pragma unroll
      for (int ln = 0; ln < HR + 2; ++ln) pf[ln] = 0.f;
    }
    const ull *pHt = nullptr, *pDt = nullptr, *pHb = nullptr, *pDb = nullptr;
    ull vHt = 0, vDt = 0, vHb = 0, vDb = 0;
    const ull* gp = nullptr; ull gv = 0;
    if (k > 0) {
      if (hasT) {
        pHt = dnH + pc + (size_t)(w - 1) * NN + j;
        pDt = dnD + pc + (size_t)(w - 1) * NN + j;
        vHt = ald(pHt);
        if (j < NN - 1) vDt = ald(pDt);
      }
      if (hasB) {
        pHb = upH + pc + (size_t)(w + 1) * NN + j;
        pDb = upD + pc + (size_t)(w + 1) * NN + j;
        vHb = ald(pHb);
        if (j < NN - 1) vDb = ald(pDb);
      }
      if (j < NW) { gp = ringp + j * 16; gv = ald(gp); }   // gather sample
    }
    asm volatile("" ::: "memory");

    // ---- part A mid: dHdt rows a..a+3 (halo-free; hides sample RTs)
    float dHdt[HR + 2];
#pragma unroll
    for (int ln = 1; ln <= HR; ++ln) {
      int i = a - 1 + ln;
      float v = 0.f;
      if (i > 0 && i < NN - 1 && j > 0 && j < NN - 1) {
        int li = ln + 1;
        float zc = Zs2[p][li][j];
        float zw = Zs2[p][li][j - 1];
        float ze = Zs2[p][li][j + 1];
        float zn = Zs2[p][li - 1][j];
        float zs_ = Zs2[p][li + 1][j];
        float d00 = DB[ln][j - 1], d01 = DB[ln][j];
        float d10 = DB[ln + 1][j - 1], d11 = DB[ln + 1][j];
        v = C_Q * (((d01 + d11) * (ze - zc) - (d00 + d10) * (zc - zw)) +
                   ((d10 + d11) * (zs_ - zc) - (d00 + d01) * (zc - zn)));
      }
      dHdt[ln] = v;
    }

    // ---- neighbor halo tag checks + staging (NO gather here)
    if (k > 0) {
      if (pHt) {
        while ((unsigned)(vHt >> 32) < (unsigned)k) {
          __builtin_amdgcn_s_sleep(1); vHt = ald(pHt);
        }
        if (j < NN - 1)
          while ((unsigned)(vDt >> 32) < (unsigned)k) {
            __builtin_amdgcn_s_sleep(1); vDt = ald(pDt);
          }
      }
      if (pHb) {
        while ((unsigned)(vHb >> 32) < (unsigned)k) {
          __builtin_amdgcn_s_sleep(1); vHb = ald(pHb);
        }
        if (j < NN - 1)
          while ((unsigned)(vDb >> 32) < (unsigned)k) {
            __builtin_amdgcn_s_sleep(1); vDb = ald(pDb);
          }
      }
      // stage halos into LDS
      if (pHt) {
        Zs2[p][0][j] = ztreg[0] + __uint_as_float((unsigned)vHt);
        if (j < NN - 1) DB[0][j] = __uint_as_float((unsigned)vDt);
      }
      if (pHb) {
        Zs2[p][HR + 3][j] = ztreg[HR + 3] + __uint_as_float((unsigned)vHb);
        if (j < NN - 1) DB[HR + 2][j] = __uint_as_float((unsigned)vDb);
      }
    }
    __syncthreads();                  // sync1: neighbor halos visible (local!)

    // ---- gather waves (0,1): spin on ring, publish tagged LDS word.
    //      Overlaps the other 6 waves' edge-row compute below.
    if (k > 0 && j < NW) {
      while ((unsigned)(gv >> 32) < (unsigned)k) {
        __builtin_amdgcn_s_sleep(1); gv = ald(gp);
      }
      float lm = __uint_as_float((unsigned)gv);
      for (int off = 32; off; off >>= 1) lm = fmaxf(lm, __shfl_xor(lm, off));
      if (lane == 0)
        lst(&gm[j >> 6], ((ull)(unsigned)k << 32) | (ull)__float_as_uint(lm));
    }

    // ---- part A edges: dHdt rows a-1, a+4 (uses staged halos)
#pragma unroll
    for (int ln = 0; ln <= HR + 1; ln += HR + 1) {
      int i = a - 1 + ln;
      float v = 0.f;
      if (i > 0 && i < NN - 1 && j > 0 && j < NN - 1) {
        int li = ln + 1;
        float zc = Zs2[p][li][j];
        float zw = Zs2[p][li][j - 1];
        float ze = Zs2[p][li][j + 1];
        float zn = Zs2[p][li - 1][j];
        float zs_ = Zs2[p][li + 1][j];
        float d00 = DB[ln][j - 1], d01 = DB[ln][j];
        float d10 = DB[ln + 1][j - 1], d11 = DB[ln + 1][j];
        v = C_Q * (((d01 + d11) * (ze - zc) - (d00 + d10) * (zc - zw)) +
                   ((d10 + d11) * (zs_ - zc) - (d00 + d01) * (zc - zn)));
      }
      dHdt[ln] = v;
    }

    // ---- dt-independent sum (so part B is a single fma per row)
    float sd[HR + 2];
#pragma unroll
    for (int ln = 0; ln < HR + 2; ++ln) sd[ln] = dHdt[ln] + smbreg[ln];

    // ---- dt: spin on the tagged LDS gather words (cheap, no barrier)
    float maxD;
    if (k == 0) {
      maxD = 1e-10f;
    } else {
      ull g0 = lld(&gm[0]);
      while ((unsigned)(g0 >> 32) < (unsigned)k) {
        __builtin_amdgcn_s_sleep(1); g0 = lld(&gm[0]);
      }
      ull g1 = lld(&gm[1]);
      while ((unsigned)(g1 >> 32) < (unsigned)k) {
        __builtin_amdgcn_s_sleep(1); g1 = lld(&gm[1]);
      }
      maxD = fmaxf(__uint_as_float((unsigned)g0),
                   __uint_as_float((unsigned)g1));
    }
    float dt = fminf(40000.0f / (2.7f * maxD), 1.0f);
    float tnew = time + dt;
    bool cap1 = (!s1) && (tnew >= 120.0f);
    bool cap2 = (!s2) && (tnew >= 160.0f);
    bool do_upd = (tnew - t_last) >= 5.0f;

    // ---- part B: H update, EARLY tagged H-halo posts, captures, smb
    float hnxt[HR + 2];
#pragma unroll
    for (int ln = 0; ln < HR + 2; ++ln) {
      int i = a - 1 + ln;
      float hnew = 0.f;
      if (i >= 0 && i < NN) {
        if (i > 0 && i < NN - 1 && j > 0 && j < NN - 1)
          hnew = fmaxf(fmaf(dt, sd[ln], hcur[ln]), 0.f);
        float zsn = ztreg[ln + 1] + hnew;
        HnB[ln][j] = hnew;
        Zs2[p ^ 1][ln + 1][j] = zsn;
        if (ln == 2) asto(upH + pn + wofs + j, tg | (ull)__float_as_uint(hnew));
        if (ln == 3) asto(dnH + pn + wofs + j, tg | (ull)__float_as_uint(hnew));
        if (i >= a && i < a + HR) {
          int id = i * NN + j;
          if (cap1) out[id] = hnew;
          if (cap2) out[MM + id] = hnew;
        }
        if (do_upd)
          smbreg[ln] = pf[ln] - 0.5f * fmaxf(TmTs - 0.006f * zsn, 0.f);
      }
      hnxt[ln] = hnew;
    }
    __syncthreads();                            // sync2: HnB/Zs2^1 visible

    // ---- phase 2: new D rows a-1..a+3 + EARLY tagged D-halo posts + max
    float lmax = 0.f;
#pragma unroll
    for (int ln = 0; ln < HR + 1; ++ln) {
      int r = a - 1 + ln;
      if (r >= 0 && r < NN - 1 && j < NN - 1) {
        float h00 = HnB[ln][j], h01 = HnB[ln][j + 1];
        float h10 = HnB[ln + 1][j], h11 = HnB[ln + 1][j + 1];
        float z00 = Zs2[p ^ 1][ln + 1][j], z01 = Zs2[p ^ 1][ln + 1][j + 1];
        float z10 = Zs2[p ^ 1][ln + 2][j], z11 = Zs2[p ^ 1][ln + 2][j + 1];
        float havg = 0.25f * (((h00 + h11) + h01) + h10);
        float u = (z01 - z00) + (z11 - z10);
        float vv = (z10 - z00) + (z11 - z01);
        float s2 = C_S2 * (u * u + vv * vv) + 1e-10f;   // == Snorm^2
        float h2 = havg * havg;
        float h4 = h2 * h2;
        float h5 = h4 * havg;
        float d = CDIF * h5 * s2 + 1e-10f;
        DB[ln + 1][j] = d;
        if (ln == 1) asto(upD + pn + wofs + j, tg | (ull)__float_as_uint(d));
        if (ln == 3) asto(dnD + pn + wofs + j, tg | (ull)__float_as_uint(d));
        lmax = fmaxf(lmax, d);
      }
    }
    for (int off = 32; off; off >>= 1) lmax = fmaxf(lmax, __shfl_xor(lmax, off));
    // pre-barrier ring post: last-arriving wave publishes the block max
    if (lane == 0) {
      atomicMax(&lmx[k & 1], __float_as_uint(lmax));   // D>0: uint-monotone
      unsigned c = atomicAdd(&lcnt[k & 1], 1u);
      if (c == 7u) {
        unsigned mv = atomicAdd(&lmx[k & 1], 0u);      // atomic read-back
        asto(ring + (size_t)((k + 1) & 1) * NW * 16 + w * 16,
             ((ull)(unsigned)(k + 1) << 32) | (ull)mv);
      }
    }

    // ---- bookkeeping + step-close barrier (protects LDS reuse next step)
#pragma unroll
    for (int ln = 0; ln < HR + 2; ++ln) hcur[ln] = hnxt[ln];
    time = tnew;
    s1 = s1 || cap1;
    s2 = s2 || cap2;
    if (do_upd) { idx = idxn; t_last = tnew; }
    __syncthreads();                            // sync3
  }

  // ---- final H (owned rows; hcur slot for row a+rr is rr+1)
#pragma unroll
  for (int rr = 0; rr < HR; ++rr)
    out[2 * MM + (a + rr) * NN + j] = hcur[rr + 1];
}

extern "C" void kernel_launch(void* const* d_in, const int* in_sizes, int n_in,
                              void* d_out, int out_size, void* d_ws, size_t ws_size,
                              hipStream_t stream) {
  const float* Zt = (const float*)d_in[0];
  const float* precip = (const float*)d_in[1];
  const float* Tm = (const float*)d_in[2];
  const float* Ts = (const float*)d_in[3];
  float* out = (float*)d_out;

  ull* ring = (ull*)d_ws;                            // 2*128 lines @ 128 B
  ull* halo = (ull*)((char*)d_ws + 32768);           // 4 MB tagged halos

  // zero ring tags + halo tags (ws is not re-poisoned between replays)
  hipMemsetAsync(d_ws, 0, 32768 + (size_t)8 * NW * NN * sizeof(ull), stream);
  glacier_kernel<<<NW, TPB, 0, stream>>>(Zt, precip, Tm, Ts, out, ring, halo);
}